// Round 25
// baseline (96.746 us; speedup 1.0000x reference)
//
#include <hip/hip_runtime.h>
#include <hip/hip_bf16.h>

// attention_11269994185437: B=4, C=256, CQK=32, H=W=64 -> N=4096
// out = gamma * (V @ P) + x,  P[n,m] = softmax over m of S[n,m], S = Q^T K.
// Qt pre-scaled by L2E: S' = L2E*S. cbias[b][n] = -log2(sum_m exp2(S'[n,m])).
// E materialized in fp8, BLOCK-CONTIGUOUS: per (b, m-tile-32) a 128 KB region;
// per n-group g (32 n): 1024 B = [h 2][m 32][evslot 2][8B].
//   k_emat: streaming S->exp2->fp8, one 16B coalesced store per tile per lane.
//   k_pv:   pure fp8 GEMM out^T = E^T*V^T; 512-thr blocks (8 waves, c-slice
//           32/wave, acc[1]) -> 16 waves/CU; linear E stream, register
//           prefetch depth 8 on both streams; fused transpose+residual.

#define NB 4
#define CC 256
#define NN 4096
#define L2E 1.44269504088896340f

typedef short  short4v  __attribute__((ext_vector_type(4)));
typedef short  short8v  __attribute__((ext_vector_type(8)));
typedef __bf16 bf16x8   __attribute__((ext_vector_type(8)));
typedef float  f32x4    __attribute__((ext_vector_type(4)));
typedef float  f32x16   __attribute__((ext_vector_type(16)));
typedef unsigned long u64x2 __attribute__((ext_vector_type(2)));
typedef unsigned int u32;
typedef unsigned long u64;

static __device__ __forceinline__ unsigned short f2bf(float f) {
  union { __bf16 h; unsigned short u; } v; v.h = (__bf16)f; return v.u;
}
static __device__ __forceinline__ float bf2f(unsigned short u) {
  union { unsigned u; float f; } v; v.u = (u32)u << 16; return v.f;
}

union FragU { short8v s; bf16x8 b; unsigned u[4]; };

static __device__ __forceinline__ bf16x8 ld_frag(const unsigned short* p) {
  FragU u; u.s = *(const short8v*)p; return u.b;
}

static __device__ __forceinline__ f32x16 zero16() {
  f32x16 v;
#pragma unroll
  for (int i = 0; i < 16; ++i) v[i] = 0.0f;
  return v;
}

static __device__ __forceinline__ f32x16 mfma32(bf16x8 a, bf16x8 b, f32x16 c) {
  return __builtin_amdgcn_mfma_f32_32x32x16_bf16(a, b, c, 0, 0, 0);
}
static __device__ __forceinline__ f32x16 mfma8(long a, long b, f32x16 c) {
  return __builtin_amdgcn_mfma_f32_32x32x16_fp8_fp8(a, b, c, 0, 0, 0);
}

// ---------------- Kernel 0: W -> bf16 row-major [320][256] ----------------
__global__ __launch_bounds__(256) void k_wcvt(
    const float* __restrict__ Wq, const float* __restrict__ Wk,
    const float* __restrict__ Wv, unsigned short* __restrict__ Wb)
{
  const int i4 = blockIdx.x * 256 + threadIdx.x;     // 80 blocks
  const int e = i4 * 4;
  const int row = e >> 8, c = e & 255;
  const float* src = (row < 32) ? (Wq + row * 256 + c)
                   : (row < 64) ? (Wk + (row - 32) * 256 + c)
                                : (Wv + (row - 64) * 256 + c);
  f32x4 v = *(const f32x4*)src;
  short4v s;
#pragma unroll
  for (int j = 0; j < 4; ++j) s[j] = (short)f2bf(v[j]);
  *(short4v*)(Wb + e) = s;
}

// ---------------- Kernel 1: QKV projection --------------------------------
// Qt[b][n][32] bf16 (L2E-scaled), Kt[b][n][32] bf16,
// V8[b][n>>5][(n>>3)&1][c][((n>>4)&1)*8 + (n&7)] fp8 e4m3.
__global__ __launch_bounds__(256) void k_proj(
    const float* __restrict__ x, const unsigned short* __restrict__ Wb,
    const float* __restrict__ bq, const float* __restrict__ bk,
    const float* __restrict__ bv,
    unsigned short* __restrict__ Qt, unsigned short* __restrict__ Kt,
    unsigned char* __restrict__ V8)
{
  __shared__ unsigned short xs[32][268];   // xs[n_local][c]
  const int t = threadIdx.x;
  const int b = blockIdx.y;
  const int n0 = blockIdx.x * 32;
  const int w = t >> 6, l = t & 63, h = l >> 5, col = l & 31;

  const float* xb = x + (size_t)b * CC * NN;
  {
    const int c_off = t >> 3, nl = 4 * (t & 7);
#pragma unroll
    for (int c0 = 0; c0 < CC; c0 += 32) {
      int c = c0 + c_off;
      f32x4 v4 = *(const f32x4*)(xb + (size_t)c * NN + n0 + nl);
#pragma unroll
      for (int j = 0; j < 4; ++j) xs[nl + j][c] = f2bf(v4[j]);
    }
  }
  __syncthreads();

  for (int f = w; f < 10; f += 4) {
    const float* bsrc; int rowbase; int mode; int wrow;
    if (f == 0)      { bsrc = bq; rowbase = 0;            mode = 0; wrow = 0; }
    else if (f == 1) { bsrc = bk; rowbase = 0;            mode = 1; wrow = 32; }
    else             { bsrc = bv; rowbase = (f - 2) * 32; mode = 2; wrow = 64 + rowbase; }

    f32x16 acc0 = zero16();
    const unsigned short* wr = Wb + (size_t)(wrow + col) * 256 + 8 * h;

#pragma unroll
    for (int k0 = 0; k0 < CC; k0 += 16) {
      FragU a;
      a.s = *(const short8v*)(wr + k0);
      const unsigned short* p0 = &xs[col][k0 + 8 * h];
      FragU b0;
      short4v t0a = *(const short4v*)p0, t0b = *(const short4v*)(p0 + 4);
#pragma unroll
      for (int j = 0; j < 4; ++j) { b0.s[j] = t0a[j]; b0.s[4 + j] = t0b[j]; }
      acc0 = mfma32(a.b, b0.b, acc0);
    }

    const int n = n0 + col;
#pragma unroll
    for (int q = 0; q < 4; ++q) {
      f32x4 bias4 = *(const f32x4*)(bsrc + rowbase + 8 * q + 4 * h);
      float vals[4];
#pragma unroll
      for (int i = 0; i < 4; ++i) vals[i] = acc0[4 * q + i] + bias4[i];
      if (mode == 2) {
        const size_t tb = ((((size_t)b * 128 + (n >> 5)) * 2 + ((n >> 3) & 1)) * 256) * 16
                          + ((n >> 4) & 1) * 8 + (n & 7);
        u32 w01 = __builtin_amdgcn_cvt_pk_fp8_f32(vals[0], vals[1], 0, false);
        u32 w23 = __builtin_amdgcn_cvt_pk_fp8_f32(vals[2], vals[3], 0, false);
        const int cb0 = rowbase + 8 * q + 4 * h;
        V8[tb + (size_t)(cb0 + 0) * 16] = (unsigned char)(w01 & 0xff);
        V8[tb + (size_t)(cb0 + 1) * 16] = (unsigned char)((w01 >> 8) & 0xff);
        V8[tb + (size_t)(cb0 + 2) * 16] = (unsigned char)(w23 & 0xff);
        V8[tb + (size_t)(cb0 + 3) * 16] = (unsigned char)((w23 >> 8) & 0xff);
      } else {
        unsigned short* dst = (mode == 0) ? Qt : Kt;
        const float scale = (mode == 0) ? L2E : 1.0f;   // fold L2E into Q
        short4v s4;
#pragma unroll
        for (int i = 0; i < 4; ++i) s4[i] = (short)f2bf(vals[i] * scale);
        *(short4v*)(dst + ((size_t)b * NN + n) * 32 + 8 * q + 4 * h) = s4;
      }
    }
  }
}

// ---------------- Kernel 2: row sums -> cbias (transposed MFMA) -----------
__global__ __launch_bounds__(512) void k_rowstats(
    const unsigned short* __restrict__ Qt, const unsigned short* __restrict__ Kt,
    float* __restrict__ cbias)
{
  __shared__ float ssum[8][64];
  const int t = threadIdx.x;
  const int w = t >> 6, l = t & 63, h = l >> 5, col = l & 31;
  const int b = blockIdx.y;
  const int n0 = blockIdx.x * 64;
  const unsigned short* Qb = Qt + (size_t)b * NN * 32;
  const unsigned short* Kb = Kt + (size_t)b * NN * 32;

  bf16x8 bq00 = ld_frag(Qb + (size_t)(n0 + col) * 32 + 8 * h);
  bf16x8 bq01 = ld_frag(Qb + (size_t)(n0 + col) * 32 + 16 + 8 * h);
  bf16x8 bq10 = ld_frag(Qb + (size_t)(n0 + 32 + col) * 32 + 8 * h);
  bf16x8 bq11 = ld_frag(Qb + (size_t)(n0 + 32 + col) * 32 + 16 + 8 * h);

  float acc0 = 0.0f, acc1 = 0.0f;
  const int mbase = w * (NN / 8);
#pragma unroll 2
  for (int mt = 0; mt < 16; ++mt) {
    const int m0 = mbase + mt * 32;
    bf16x8 ak0 = ld_frag(Kb + (size_t)(m0 + col) * 32 + 8 * h);
    bf16x8 ak1 = ld_frag(Kb + (size_t)(m0 + col) * 32 + 16 + 8 * h);
    f32x16 S0 = zero16(), S1 = zero16();
    S0 = mfma32(ak0, bq00, S0);
    S0 = mfma32(ak1, bq01, S0);
    S1 = mfma32(ak0, bq10, S1);
    S1 = mfma32(ak1, bq11, S1);
    float p0 = 0.0f, p1 = 0.0f, p2 = 0.0f, p3 = 0.0f;
#pragma unroll
    for (int r = 0; r < 8; ++r) {
      p0 += __builtin_amdgcn_exp2f(S0[r]);
      p1 += __builtin_amdgcn_exp2f(S0[8 + r]);
      p2 += __builtin_amdgcn_exp2f(S1[r]);
      p3 += __builtin_amdgcn_exp2f(S1[8 + r]);
    }
    acc0 += p0 + p1;
    acc1 += p2 + p3;
  }
  acc0 += __shfl_xor(acc0, 32);
  acc1 += __shfl_xor(acc1, 32);

  if (l < 32) { ssum[w][l] = acc0; ssum[w][32 + l] = acc1; }
  __syncthreads();

  if (t < 64) {
    float s = 0.0f;
#pragma unroll
    for (int wv = 0; wv < 8; ++wv) s += ssum[wv][t];
    cbias[(size_t)b * NN + n0 + t] = -__builtin_amdgcn_logf(s);
  }
}

// ---------------- Kernel 3: E materialization (streaming) -----------------
// grid (N/32, B), 512 thr (8 waves). E8 region per (b, mt=m>>5): 128 KB.
// byte = (b*128 + mt)*131072 + g*1024 + h*512 + (m&31)*16 + sl*8, g = n>>5.
__global__ __launch_bounds__(512) void k_emat(
    const unsigned short* __restrict__ Qt, const unsigned short* __restrict__ Kt,
    const float* __restrict__ cbias, unsigned char* __restrict__ E8)
{
  const int t = threadIdx.x;
  const int w = t >> 6, l = t & 63, h = l >> 5, col = l & 31;
  const int b = blockIdx.y;
  const int n0 = blockIdx.x * 32;
  const unsigned short* Qb = Qt + (size_t)b * NN * 32;
  const unsigned short* Kb = Kt + (size_t)b * NN * 32;

  bf16x8 aq0 = ld_frag(Qb + (size_t)(n0 + col) * 32 + 8 * h);
  bf16x8 aq1 = ld_frag(Qb + (size_t)(n0 + col) * 32 + 16 + 8 * h);

  f32x4 cb4[4];
  const float* cbi = cbias + (size_t)b * NN + n0;
#pragma unroll
  for (int q = 0; q < 4; ++q) cb4[q] = *(const f32x4*)(cbi + 8 * q + 4 * h);

  const size_t gh_off = (size_t)(n0 >> 5) * 1024 + (size_t)h * 512 + (size_t)col * 16;

#pragma unroll 2
  for (int mt = 0; mt < 16; ++mt) {
    const int m0 = w * 512 + mt * 32;
    bf16x8 bk0 = ld_frag(Kb + (size_t)(m0 + col) * 32 + 8 * h);
    bf16x8 bk1 = ld_frag(Kb + (size_t)(m0 + col) * 32 + 16 + 8 * h);
    f32x16 S = zero16();
    S = mfma32(aq0, bk0, S);
    S = mfma32(aq1, bk1, S);

    float e[16];
#pragma unroll
    for (int q = 0; q < 4; ++q)
#pragma unroll
      for (int i = 0; i < 4; ++i)
        e[4 * q + i] = __builtin_amdgcn_exp2f(S[4 * q + i] + cb4[q][i]);

    u32 wA = __builtin_amdgcn_cvt_pk_fp8_f32(e[0], e[1], 0, false);
    wA = __builtin_amdgcn_cvt_pk_fp8_f32(e[2], e[3], wA, true);
    u32 wB = __builtin_amdgcn_cvt_pk_fp8_f32(e[4], e[5], 0, false);
    wB = __builtin_amdgcn_cvt_pk_fp8_f32(e[6], e[7], wB, true);
    u32 wC = __builtin_amdgcn_cvt_pk_fp8_f32(e[8], e[9], 0, false);
    wC = __builtin_amdgcn_cvt_pk_fp8_f32(e[10], e[11], wC, true);
    u32 wD = __builtin_amdgcn_cvt_pk_fp8_f32(e[12], e[13], 0, false);
    wD = __builtin_amdgcn_cvt_pk_fp8_f32(e[14], e[15], wD, true);
    asm("v_permlane32_swap_b32 %0, %1" : "+v"(wA), "+v"(wB));
    asm("v_permlane32_swap_b32 %0, %1" : "+v"(wC), "+v"(wD));
    u64x2 ev;
    ev[0] = ((u64)wB << 32) | wA;   // n' 0..15 of the 32-n group
    ev[1] = ((u64)wD << 32) | wC;   // n' 16..31

    unsigned char* st = E8 + ((size_t)b * 128 + (size_t)(w * 16 + mt)) * 131072 + gh_off;
    *(u64x2*)st = ev;
  }
}

// ---------------- Kernel 4: fp8 GEMM out^T = E^T * V^T, 8-wave blocks -----
// grid (N/32, B) = 512 blocks (2/CU), 512 thr (8 waves) -> 16 waves/CU.
// Wave w: c-slice w*32, acc[1] (16 regs). Per iter: 1 E dwordx4 (shared
// stream, L1-dedup), 1 V dwordx4, 2 MFMAs. Both streams prefetch depth 8.
__global__ __launch_bounds__(512) void k_pv(
    const unsigned char* __restrict__ E8, const unsigned char* __restrict__ V8,
    const float* __restrict__ x, const float* __restrict__ gamma,
    float* __restrict__ out)
{
  __shared__ unsigned short ldb[32][264];
  const int t = threadIdx.x;
  const int w = t >> 6, l = t & 63, h = l >> 5, col = l & 31;
  const int b = blockIdx.y;
  const int m0 = blockIdx.x * 32;
  const int cc = w * 32;

  const unsigned char* ep = E8 + ((size_t)b * 128 + blockIdx.x) * 131072
                            + (size_t)h * 512 + (size_t)col * 16;
  const unsigned char* vp = V8 + ((size_t)b * 256 + h) * 4096
                            + (size_t)(cc + col) * 16;

  f32x16 acc = zero16();

  u64x2 ePf[8], vAp[8];
#pragma unroll
  for (int s = 0; s < 8; ++s) {
    ePf[s] = *(const u64x2*)(ep + (size_t)s * 1024);
    vAp[s] = *(const u64x2*)(vp + (size_t)s * 8192);
  }

  for (int gg = 0; gg < 128; gg += 8) {
#pragma unroll
    for (int s = 0; s < 8; ++s) {
      const int gn = gg + 8 + s;
      // issue next loads first (depth 8; overrun reads stay inside d_ws,
      // never consumed)
      u64x2 nE = *(const u64x2*)(ep + (size_t)gn * 1024);
      u64x2 nvA = *(const u64x2*)(vp + (size_t)gn * 8192);
      acc = mfma8((long)ePf[s][0], (long)vAp[s][0], acc);
      acc = mfma8((long)ePf[s][1], (long)vAp[s][1], acc);
      ePf[s] = nE; vAp[s] = nvA;
    }
  }

  // stage out^T tile (32m x 256c) to LDS as bf16 (wave w -> c-slice cc)
#pragma unroll
  for (int r = 0; r < 16; ++r) {
    int mloc = (r & 3) + 8 * (r >> 2) + 4 * h;
    ldb[mloc][cc + col] = f2bf(acc[r]);
  }
  __syncthreads();

  // transpose-read + residual: out[b][c][m0+..] = g*val + x (512 thr)
  const float g = gamma[0];
  const int ci = t >> 1;            // 0..255
  const int mh = (t & 1) * 16;      // 0 or 16
  const size_t base = ((size_t)b * CC + ci) * NN + m0 + mh;
#pragma unroll
  for (int k4 = 0; k4 < 4; ++k4) {
    const size_t idx = base + 4 * k4;
    f32x4 xv = *(const f32x4*)(x + idx);
    f32x4 o;
#pragma unroll
    for (int k = 0; k < 4; ++k) o[k] = g * bf2f(ldb[mh + 4 * k4 + k][ci]) + xv[k];
    *(f32x4*)(out + idx) = o;
  }
}

// ---------------- launch ---------------------------------------------------
extern "C" void kernel_launch(void* const* d_in, const int* in_sizes, int n_in,
                              void* d_out, int out_size, void* d_ws, size_t ws_size,
                              hipStream_t stream) {
  const float* x     = (const float*)d_in[0];
  const float* Wq    = (const float*)d_in[1];
  const float* bq    = (const float*)d_in[2];
  const float* Wk    = (const float*)d_in[3];
  const float* bk    = (const float*)d_in[4];
  const float* Wv    = (const float*)d_in[5];
  const float* bv    = (const float*)d_in[6];
  const float* gamma = (const float*)d_in[7];
  float* out = (float*)d_out;

  char* ws = (char*)d_ws;
  unsigned short* Qt = (unsigned short*)(ws);                      // 1 MB
  unsigned short* Kt = (unsigned short*)(ws + (1u << 20));         // 1 MB
  unsigned char*  V8 = (unsigned char*)(ws + (2u << 20));          // 4 MB
  unsigned short* Wb = (unsigned short*)(ws + (6u << 20));         // 160 KB
  float* cbias = (float*)(ws + (6u << 20) + (1u << 18));           // 64 KB
  unsigned char* E8  = (unsigned char*)(ws + (7u << 20));          // 64 MB

  k_wcvt<<<dim3(80), 256, 0, stream>>>(Wq, Wk, Wv, Wb);
  k_proj<<<dim3(NN / 32, NB), 256, 0, stream>>>(x, Wb, bq, bk, bv, Qt, Kt, V8);
  k_rowstats<<<dim3(NN / 64, NB), 512, 0, stream>>>(Qt, Kt, cbias);
  k_emat<<<dim3(NN / 32, NB), 512, 0, stream>>>(Qt, Kt, cbias, E8);
  k_pv<<<dim3(NN / 32, NB), 512, 0, stream>>>(E8, V8, x, gamma, out);
}

// Round 26
// 88.287 us; speedup vs baseline: 1.0958x; 1.0958x over previous
//
#include <hip/hip_runtime.h>
#include <hip/hip_bf16.h>

// attention_11269994185437: B=4, C=256, CQK=32, H=W=64 -> N=4096
// out = gamma * (V @ P) + x,  P[n,m] = softmax over m of S[n,m], S = Q^T K.
// Qt pre-scaled by L2E: S' = L2E*S. cbias[b][n] = -log2(sum_m exp2(S'[n,m])).
// E materialized in fp8, BLOCK-CONTIGUOUS: per (b, m-tile-32) a 128 KB region;
// per n-group g (32 n): 1024 B = [h 2][m 32][evslot 2][8B] (e0,e1 adjacent:
// one dwordx4 per lane on both store and load).
//   k_emat: streaming S->exp2->fp8, one 16B coalesced store per tile per lane.
//   k_pv:   pure fp8 GEMM out^T = E^T*V^T; linear E stream, prefetch depth 8
//           (register-resident: the measured optimum -- depth 16 and 8-wave
//           variants both spill, LDS-staging adds barrier drains), fused
//           transpose+residual epilogue. [R23 configuration, 88.55 us]

#define NB 4
#define CC 256
#define NN 4096
#define L2E 1.44269504088896340f

typedef short  short4v  __attribute__((ext_vector_type(4)));
typedef short  short8v  __attribute__((ext_vector_type(8)));
typedef __bf16 bf16x8   __attribute__((ext_vector_type(8)));
typedef float  f32x4    __attribute__((ext_vector_type(4)));
typedef float  f32x16   __attribute__((ext_vector_type(16)));
typedef unsigned long u64x2 __attribute__((ext_vector_type(2)));
typedef unsigned int u32;
typedef unsigned long u64;

static __device__ __forceinline__ unsigned short f2bf(float f) {
  union { __bf16 h; unsigned short u; } v; v.h = (__bf16)f; return v.u;
}
static __device__ __forceinline__ float bf2f(unsigned short u) {
  union { unsigned u; float f; } v; v.u = (u32)u << 16; return v.f;
}

union FragU { short8v s; bf16x8 b; unsigned u[4]; };

static __device__ __forceinline__ bf16x8 ld_frag(const unsigned short* p) {
  FragU u; u.s = *(const short8v*)p; return u.b;
}

static __device__ __forceinline__ f32x16 zero16() {
  f32x16 v;
#pragma unroll
  for (int i = 0; i < 16; ++i) v[i] = 0.0f;
  return v;
}

static __device__ __forceinline__ f32x16 mfma32(bf16x8 a, bf16x8 b, f32x16 c) {
  return __builtin_amdgcn_mfma_f32_32x32x16_bf16(a, b, c, 0, 0, 0);
}
static __device__ __forceinline__ f32x16 mfma8(long a, long b, f32x16 c) {
  return __builtin_amdgcn_mfma_f32_32x32x16_fp8_fp8(a, b, c, 0, 0, 0);
}

// ---------------- Kernel 0: W -> bf16 row-major [320][256] ----------------
__global__ __launch_bounds__(256) void k_wcvt(
    const float* __restrict__ Wq, const float* __restrict__ Wk,
    const float* __restrict__ Wv, unsigned short* __restrict__ Wb)
{
  const int i4 = blockIdx.x * 256 + threadIdx.x;     // 80 blocks
  const int e = i4 * 4;
  const int row = e >> 8, c = e & 255;
  const float* src = (row < 32) ? (Wq + row * 256 + c)
                   : (row < 64) ? (Wk + (row - 32) * 256 + c)
                                : (Wv + (row - 64) * 256 + c);
  f32x4 v = *(const f32x4*)src;
  short4v s;
#pragma unroll
  for (int j = 0; j < 4; ++j) s[j] = (short)f2bf(v[j]);
  *(short4v*)(Wb + e) = s;
}

// ---------------- Kernel 1: QKV projection --------------------------------
// Qt[b][n][32] bf16 (L2E-scaled), Kt[b][n][32] bf16,
// V8[b][n>>5][(n>>3)&1][c][((n>>4)&1)*8 + (n&7)] fp8 e4m3.
__global__ __launch_bounds__(256) void k_proj(
    const float* __restrict__ x, const unsigned short* __restrict__ Wb,
    const float* __restrict__ bq, const float* __restrict__ bk,
    const float* __restrict__ bv,
    unsigned short* __restrict__ Qt, unsigned short* __restrict__ Kt,
    unsigned char* __restrict__ V8)
{
  __shared__ unsigned short xs[32][268];   // xs[n_local][c]
  const int t = threadIdx.x;
  const int b = blockIdx.y;
  const int n0 = blockIdx.x * 32;
  const int w = t >> 6, l = t & 63, h = l >> 5, col = l & 31;

  const float* xb = x + (size_t)b * CC * NN;
  {
    const int c_off = t >> 3, nl = 4 * (t & 7);
#pragma unroll
    for (int c0 = 0; c0 < CC; c0 += 32) {
      int c = c0 + c_off;
      f32x4 v4 = *(const f32x4*)(xb + (size_t)c * NN + n0 + nl);
#pragma unroll
      for (int j = 0; j < 4; ++j) xs[nl + j][c] = f2bf(v4[j]);
    }
  }
  __syncthreads();

  for (int f = w; f < 10; f += 4) {
    const float* bsrc; int rowbase; int mode; int wrow;
    if (f == 0)      { bsrc = bq; rowbase = 0;            mode = 0; wrow = 0; }
    else if (f == 1) { bsrc = bk; rowbase = 0;            mode = 1; wrow = 32; }
    else             { bsrc = bv; rowbase = (f - 2) * 32; mode = 2; wrow = 64 + rowbase; }

    f32x16 acc0 = zero16();
    const unsigned short* wr = Wb + (size_t)(wrow + col) * 256 + 8 * h;

#pragma unroll
    for (int k0 = 0; k0 < CC; k0 += 16) {
      FragU a;
      a.s = *(const short8v*)(wr + k0);
      const unsigned short* p0 = &xs[col][k0 + 8 * h];
      FragU b0;
      short4v t0a = *(const short4v*)p0, t0b = *(const short4v*)(p0 + 4);
#pragma unroll
      for (int j = 0; j < 4; ++j) { b0.s[j] = t0a[j]; b0.s[4 + j] = t0b[j]; }
      acc0 = mfma32(a.b, b0.b, acc0);
    }

    const int n = n0 + col;
#pragma unroll
    for (int q = 0; q < 4; ++q) {
      f32x4 bias4 = *(const f32x4*)(bsrc + rowbase + 8 * q + 4 * h);
      float vals[4];
#pragma unroll
      for (int i = 0; i < 4; ++i) vals[i] = acc0[4 * q + i] + bias4[i];
      if (mode == 2) {
        const size_t tb = ((((size_t)b * 128 + (n >> 5)) * 2 + ((n >> 3) & 1)) * 256) * 16
                          + ((n >> 4) & 1) * 8 + (n & 7);
        u32 w01 = __builtin_amdgcn_cvt_pk_fp8_f32(vals[0], vals[1], 0, false);
        u32 w23 = __builtin_amdgcn_cvt_pk_fp8_f32(vals[2], vals[3], 0, false);
        const int cb0 = rowbase + 8 * q + 4 * h;
        V8[tb + (size_t)(cb0 + 0) * 16] = (unsigned char)(w01 & 0xff);
        V8[tb + (size_t)(cb0 + 1) * 16] = (unsigned char)((w01 >> 8) & 0xff);
        V8[tb + (size_t)(cb0 + 2) * 16] = (unsigned char)(w23 & 0xff);
        V8[tb + (size_t)(cb0 + 3) * 16] = (unsigned char)((w23 >> 8) & 0xff);
      } else {
        unsigned short* dst = (mode == 0) ? Qt : Kt;
        const float scale = (mode == 0) ? L2E : 1.0f;   // fold L2E into Q
        short4v s4;
#pragma unroll
        for (int i = 0; i < 4; ++i) s4[i] = (short)f2bf(vals[i] * scale);
        *(short4v*)(dst + ((size_t)b * NN + n) * 32 + 8 * q + 4 * h) = s4;
      }
    }
  }
}

// ---------------- Kernel 2: row sums -> cbias (transposed MFMA) -----------
__global__ __launch_bounds__(512) void k_rowstats(
    const unsigned short* __restrict__ Qt, const unsigned short* __restrict__ Kt,
    float* __restrict__ cbias)
{
  __shared__ float ssum[8][64];
  const int t = threadIdx.x;
  const int w = t >> 6, l = t & 63, h = l >> 5, col = l & 31;
  const int b = blockIdx.y;
  const int n0 = blockIdx.x * 64;
  const unsigned short* Qb = Qt + (size_t)b * NN * 32;
  const unsigned short* Kb = Kt + (size_t)b * NN * 32;

  bf16x8 bq00 = ld_frag(Qb + (size_t)(n0 + col) * 32 + 8 * h);
  bf16x8 bq01 = ld_frag(Qb + (size_t)(n0 + col) * 32 + 16 + 8 * h);
  bf16x8 bq10 = ld_frag(Qb + (size_t)(n0 + 32 + col) * 32 + 8 * h);
  bf16x8 bq11 = ld_frag(Qb + (size_t)(n0 + 32 + col) * 32 + 16 + 8 * h);

  float acc0 = 0.0f, acc1 = 0.0f;
  const int mbase = w * (NN / 8);
#pragma unroll 2
  for (int mt = 0; mt < 16; ++mt) {
    const int m0 = mbase + mt * 32;
    bf16x8 ak0 = ld_frag(Kb + (size_t)(m0 + col) * 32 + 8 * h);
    bf16x8 ak1 = ld_frag(Kb + (size_t)(m0 + col) * 32 + 16 + 8 * h);
    f32x16 S0 = zero16(), S1 = zero16();
    S0 = mfma32(ak0, bq00, S0);
    S0 = mfma32(ak1, bq01, S0);
    S1 = mfma32(ak0, bq10, S1);
    S1 = mfma32(ak1, bq11, S1);
    float p0 = 0.0f, p1 = 0.0f, p2 = 0.0f, p3 = 0.0f;
#pragma unroll
    for (int r = 0; r < 8; ++r) {
      p0 += __builtin_amdgcn_exp2f(S0[r]);
      p1 += __builtin_amdgcn_exp2f(S0[8 + r]);
      p2 += __builtin_amdgcn_exp2f(S1[r]);
      p3 += __builtin_amdgcn_exp2f(S1[8 + r]);
    }
    acc0 += p0 + p1;
    acc1 += p2 + p3;
  }
  acc0 += __shfl_xor(acc0, 32);
  acc1 += __shfl_xor(acc1, 32);

  if (l < 32) { ssum[w][l] = acc0; ssum[w][32 + l] = acc1; }
  __syncthreads();

  if (t < 64) {
    float s = 0.0f;
#pragma unroll
    for (int wv = 0; wv < 8; ++wv) s += ssum[wv][t];
    cbias[(size_t)b * NN + n0 + t] = -__builtin_amdgcn_logf(s);
  }
}

// ---------------- Kernel 3: E materialization (streaming) -----------------
// grid (N/32, B), 512 thr (8 waves). E8 region per (b, mt=m>>5): 128 KB.
// byte = (b*128 + mt)*131072 + g*1024 + h*512 + (m&31)*16 + sl*8, g = n>>5.
// One u64x2 (16B) store per tile per lane, 512B contiguous per half-wave.
__global__ __launch_bounds__(512) void k_emat(
    const unsigned short* __restrict__ Qt, const unsigned short* __restrict__ Kt,
    const float* __restrict__ cbias, unsigned char* __restrict__ E8)
{
  const int t = threadIdx.x;
  const int w = t >> 6, l = t & 63, h = l >> 5, col = l & 31;
  const int b = blockIdx.y;
  const int n0 = blockIdx.x * 32;
  const unsigned short* Qb = Qt + (size_t)b * NN * 32;
  const unsigned short* Kb = Kt + (size_t)b * NN * 32;

  bf16x8 aq0 = ld_frag(Qb + (size_t)(n0 + col) * 32 + 8 * h);
  bf16x8 aq1 = ld_frag(Qb + (size_t)(n0 + col) * 32 + 16 + 8 * h);

  f32x4 cb4[4];
  const float* cbi = cbias + (size_t)b * NN + n0;
#pragma unroll
  for (int q = 0; q < 4; ++q) cb4[q] = *(const f32x4*)(cbi + 8 * q + 4 * h);

  const size_t gh_off = (size_t)(n0 >> 5) * 1024 + (size_t)h * 512 + (size_t)col * 16;

#pragma unroll 2
  for (int mt = 0; mt < 16; ++mt) {
    const int m0 = w * 512 + mt * 32;
    bf16x8 bk0 = ld_frag(Kb + (size_t)(m0 + col) * 32 + 8 * h);
    bf16x8 bk1 = ld_frag(Kb + (size_t)(m0 + col) * 32 + 16 + 8 * h);
    f32x16 S = zero16();
    S = mfma32(aq0, bk0, S);
    S = mfma32(aq1, bk1, S);

    float e[16];
#pragma unroll
    for (int q = 0; q < 4; ++q)
#pragma unroll
      for (int i = 0; i < 4; ++i)
        e[4 * q + i] = __builtin_amdgcn_exp2f(S[4 * q + i] + cb4[q][i]);

    u32 wA = __builtin_amdgcn_cvt_pk_fp8_f32(e[0], e[1], 0, false);
    wA = __builtin_amdgcn_cvt_pk_fp8_f32(e[2], e[3], wA, true);
    u32 wB = __builtin_amdgcn_cvt_pk_fp8_f32(e[4], e[5], 0, false);
    wB = __builtin_amdgcn_cvt_pk_fp8_f32(e[6], e[7], wB, true);
    u32 wC = __builtin_amdgcn_cvt_pk_fp8_f32(e[8], e[9], 0, false);
    wC = __builtin_amdgcn_cvt_pk_fp8_f32(e[10], e[11], wC, true);
    u32 wD = __builtin_amdgcn_cvt_pk_fp8_f32(e[12], e[13], 0, false);
    wD = __builtin_amdgcn_cvt_pk_fp8_f32(e[14], e[15], wD, true);
    asm("v_permlane32_swap_b32 %0, %1" : "+v"(wA), "+v"(wB));
    asm("v_permlane32_swap_b32 %0, %1" : "+v"(wC), "+v"(wD));
    u64x2 ev;
    ev[0] = ((u64)wB << 32) | wA;   // n' 0..15 of the 32-n group
    ev[1] = ((u64)wD << 32) | wC;   // n' 16..31

    unsigned char* st = E8 + ((size_t)b * 128 + (size_t)(w * 16 + mt)) * 131072 + gh_off;
    *(u64x2*)st = ev;
  }
}

// ---------------- Kernel 4: pure fp8 GEMM out^T = E^T * V^T + epilogue ----
// grid (N/32, B) = 512 blocks (2/CU), 256 thr (4 waves).
// Block streams its 128 KB E region LINEARLY; prefetch depth 8 (registers).
__global__ __launch_bounds__(256) void k_pv(
    const unsigned char* __restrict__ E8, const unsigned char* __restrict__ V8,
    const float* __restrict__ x, const float* __restrict__ gamma,
    float* __restrict__ out)
{
  __shared__ unsigned short ldb[32][264];
  const int t = threadIdx.x;
  const int w = t >> 6, l = t & 63, h = l >> 5, col = l & 31;
  const int b = blockIdx.y;
  const int m0 = blockIdx.x * 32;
  const int cc = w * 64;

  const unsigned char* ep = E8 + ((size_t)b * 128 + blockIdx.x) * 131072
                            + (size_t)h * 512 + (size_t)col * 16;
  const unsigned char* vp = V8 + ((size_t)b * 256 + h) * 4096
                            + (size_t)(cc + col) * 16;

  f32x16 acc[2];
  acc[0] = zero16();
  acc[1] = zero16();

  u64x2 ePf[8], vAp[8], vBp[8];
#pragma unroll
  for (int s = 0; s < 8; ++s) {
    ePf[s] = *(const u64x2*)(ep + (size_t)s * 1024);
    vAp[s] = *(const u64x2*)(vp + (size_t)s * 8192);
    vBp[s] = *(const u64x2*)(vp + (size_t)s * 8192 + 512);
  }

  for (int gg = 0; gg < 128; gg += 8) {
#pragma unroll
    for (int s = 0; s < 8; ++s) {
      const int gn = gg + 8 + s;
      // issue next loads first (depth 8; overrun reads stay inside d_ws,
      // never consumed)
      u64x2 nE = *(const u64x2*)(ep + (size_t)gn * 1024);
      u64x2 nvA = *(const u64x2*)(vp + (size_t)gn * 8192);
      u64x2 nvB = *(const u64x2*)(vp + (size_t)gn * 8192 + 512);
      acc[0] = mfma8((long)ePf[s][0], (long)vAp[s][0], acc[0]);
      acc[1] = mfma8((long)ePf[s][0], (long)vBp[s][0], acc[1]);
      acc[0] = mfma8((long)ePf[s][1], (long)vAp[s][1], acc[0]);
      acc[1] = mfma8((long)ePf[s][1], (long)vBp[s][1], acc[1]);
      ePf[s] = nE; vAp[s] = nvA; vBp[s] = nvB;
    }
  }

  // stage out^T tile (32m x 256c) to LDS as bf16
#pragma unroll
  for (int cf = 0; cf < 2; ++cf)
#pragma unroll
    for (int r = 0; r < 16; ++r) {
      int mloc = (r & 3) + 8 * (r >> 2) + 4 * h;
      ldb[mloc][cc + 32 * cf + col] = f2bf(acc[cf][r]);
    }
  __syncthreads();

  // transpose-read + residual: out[b][c][m0+..] = g*val + x
  const float g = gamma[0];
  const int ci = t >> 3;           // 0..31
  const int m4 = (t & 7) * 4;      // 0..28
#pragma unroll
  for (int rnd = 0; rnd < 8; ++rnd) {
    const int c = 32 * rnd + ci;
    const size_t idx = ((size_t)b * CC + c) * NN + m0 + m4;
    f32x4 xv = *(const f32x4*)(x + idx);
    f32x4 o;
#pragma unroll
    for (int k = 0; k < 4; ++k) o[k] = g * bf2f(ldb[m4 + k][c]) + xv[k];
    *(f32x4*)(out + idx) = o;
  }
}

// ---------------- launch ---------------------------------------------------
extern "C" void kernel_launch(void* const* d_in, const int* in_sizes, int n_in,
                              void* d_out, int out_size, void* d_ws, size_t ws_size,
                              hipStream_t stream) {
  const float* x     = (const float*)d_in[0];
  const float* Wq    = (const float*)d_in[1];
  const float* bq    = (const float*)d_in[2];
  const float* Wk    = (const float*)d_in[3];
  const float* bk    = (const float*)d_in[4];
  const float* Wv    = (const float*)d_in[5];
  const float* bv    = (const float*)d_in[6];
  const float* gamma = (const float*)d_in[7];
  float* out = (float*)d_out;

  char* ws = (char*)d_ws;
  unsigned short* Qt = (unsigned short*)(ws);                      // 1 MB
  unsigned short* Kt = (unsigned short*)(ws + (1u << 20));         // 1 MB
  unsigned char*  V8 = (unsigned char*)(ws + (2u << 20));          // 4 MB
  unsigned short* Wb = (unsigned short*)(ws + (6u << 20));         // 160 KB
  float* cbias = (float*)(ws + (6u << 20) + (1u << 18));           // 64 KB
  unsigned char* E8  = (unsigned char*)(ws + (7u << 20));          // 64 MB

  k_wcvt<<<dim3(80), 256, 0, stream>>>(Wq, Wk, Wv, Wb);
  k_proj<<<dim3(NN / 32, NB), 256, 0, stream>>>(x, Wb, bq, bk, bv, Qt, Kt, V8);
  k_rowstats<<<dim3(NN / 64, NB), 512, 0, stream>>>(Qt, Kt, cbias);
  k_emat<<<dim3(NN / 32, NB), 512, 0, stream>>>(Qt, Kt, cbias, E8);
  k_pv<<<dim3(NN / 32, NB), 512 / 2, 0, stream>>>(E8, V8, x, gamma, out);
}